// Round 4
// baseline (219.995 us; speedup 1.0000x reference)
//
#include <hip/hip_runtime.h>

// Classwise circular-buffer queue update.
// occ_i = rank of proposal i within its class (original index order).
// slot  = (tail[l] + occ) % Q.  Proposal i is the FINAL writer of its slot
// iff occ >= k_l - Q.  => conflict-free scatter of proposal index into
// idx[C*Q], then one streaming gather pass building the output.

typedef float vf4 __attribute__((ext_vector_type(4)));

#define HBLK 1024  // proposals per histogram block
#define GT   256   // rows per gather tile (one block)

// Zero own cnt row, then histogram this block's labels into it.
__global__ void k_hist(const int* __restrict__ lab, int* __restrict__ cnt,
                       int N, int C) {
    int b = blockIdx.x;
    int t = threadIdx.x;
    int* row = cnt + (size_t)b * C;
    for (int j = t; j < C; j += HBLK) row[j] = 0;
    __syncthreads();
    int i = b * HBLK + t;
    if (i < N) {
        int l = lab[i];
        if (l >= 0 && l < C) atomicAdd(&row[l], 1);
    }
}

// Column-wise exclusive prefix over blocks; total per label; init idx = -1.
__global__ void k_prefix(int* __restrict__ cnt, int* __restrict__ ktot,
                         int* __restrict__ idx, int C, int NB, int Q) {
    int l = blockIdx.x * blockDim.x + threadIdx.x;
    if (l >= C) return;
    int run = 0;
    for (int b = 0; b < NB; ++b) {
        int t = cnt[(size_t)b * C + l];
        cnt[(size_t)b * C + l] = run;  // exclusive prefix per (block,label)
        run += t;
    }
    ktot[l] = run;                     // total count per label
    for (int q = 0; q < Q; ++q) idx[l * Q + q] = -1;
}

__global__ void k_slots(const int* __restrict__ lab, const int* __restrict__ tail,
                        const int* __restrict__ cnt, const int* __restrict__ ktot,
                        int* __restrict__ idx, int N, int C, int Q) {
    __shared__ int slab[HBLK];
    int b = blockIdx.x;
    int t = threadIdx.x;
    int i = b * HBLK + t;
    int l = (i < N) ? lab[i] : -1;
    slab[t] = l;
    __syncthreads();
    if (l < 0 || l >= C) return;
    int local = 0;  // rank within block (broadcast LDS reads)
    for (int j = 0; j < t; ++j) local += (slab[j] == l) ? 1 : 0;
    int occ = cnt[(size_t)b * C + l] + local;
    int kk = ktot[l];
    if (occ >= kk - Q) {
        int s = (tail[l] + occ) % Q;
        if (s < 0) s += Q;            // python-style mod (positive divisor)
        idx[l * Q + s] = i;           // unique (class,slot) per qualifier
    }
}

// Tile kernel (F==256 only): block stages GT idx values in LDS, then each
// wave copies 64 contiguous rows (sequential 64KB read/write streams; src
// address from LDS broadcast -> no global dependency in the copy loop).
__global__ void k_gather_t(const vf4* __restrict__ feat,
                           const vf4* __restrict__ queue,
                           const int* __restrict__ idx,
                           vf4* __restrict__ out, int R) {
    __shared__ int sidx[GT];
    int base = blockIdx.x * GT;
    int t = threadIdx.x;
    int nrows = R - base;
    if (nrows > GT) nrows = GT;
    if (t < nrows) sidx[t] = idx[base + t];
    __syncthreads();
    int wave = t >> 6, lane = t & 63;
    int r0 = wave * 64;
    int r1 = r0 + 64;
    if (r1 > nrows) r1 = nrows;
    #pragma unroll 4
    for (int k = r0; k < r1; ++k) {
        int id = sidx[k];  // LDS broadcast
        const vf4* src = (id >= 0) ? (feat  + ((size_t)id << 6) + lane)
                                   : (queue + ((size_t)(base + k) << 6) + lane);
        vf4 v = __builtin_nontemporal_load(src);
        __builtin_nontemporal_store(v, out + ((size_t)(base + k) << 6) + lane);
    }
}

// Generic fallback (any F divisible by 4).
__global__ void k_gather_g(const vf4* __restrict__ feat,
                           const vf4* __restrict__ queue,
                           const int* __restrict__ idx,
                           vf4* __restrict__ out,
                           long long total4, int F4) {
    long long stride = (long long)gridDim.x * blockDim.x;
    for (long long g = (long long)blockIdx.x * blockDim.x + threadIdx.x;
         g < total4; g += stride) {
        int r = (int)(g / F4);
        int c = (int)(g - (long long)r * F4);
        int id = idx[r];
        const vf4* src = (id >= 0) ? (feat + (size_t)id * F4 + c)
                                   : (queue + (size_t)r * F4 + c);
        vf4 v = __builtin_nontemporal_load(src);
        __builtin_nontemporal_store(v, &out[g]);
    }
}

extern "C" void kernel_launch(void* const* d_in, const int* in_sizes, int n_in,
                              void* d_out, int out_size, void* d_ws, size_t ws_size,
                              hipStream_t stream) {
    const float* feat  = (const float*)d_in[0];
    const float* queue = (const float*)d_in[1];
    const int*   lab   = (const int*)d_in[2];
    const int*   tail  = (const int*)d_in[3];

    const int N = in_sizes[2];
    const int C = in_sizes[3];
    const int F = in_sizes[0] / N;
    const int Q = in_sizes[1] / (C * F);
    const int NB = (N + HBLK - 1) / HBLK;

    int* idx  = (int*)d_ws;                    // C*Q
    int* cnt  = idx + (size_t)C * Q;           // NB*C
    int* ktot = cnt + (size_t)NB * C;          // C

    k_hist<<<NB, HBLK, 0, stream>>>(lab, cnt, N, C);
    k_prefix<<<(C + 255) / 256, 256, 0, stream>>>(cnt, ktot, idx, C, NB, Q);
    k_slots<<<NB, HBLK, 0, stream>>>(lab, tail, cnt, ktot, idx, N, C, Q);

    const int R = C * Q;
    if (F == 256) {
        const int blocks = (R + GT - 1) / GT;
        k_gather_t<<<blocks, GT, 0, stream>>>((const vf4*)feat,
                                              (const vf4*)queue, idx,
                                              (vf4*)d_out, R);
    } else {
        const int F4 = F / 4;
        const long long total4 = (long long)R * F4;
        int gblocks = 2048;
        long long need = (total4 + 255) / 256;
        if (need < gblocks) gblocks = (int)need;
        k_gather_g<<<gblocks, 256, 0, stream>>>((const vf4*)feat,
                                                (const vf4*)queue, idx,
                                                (vf4*)d_out, total4, F4);
    }
}

// Round 5
// 199.766 us; speedup vs baseline: 1.1013x; 1.1013x over previous
//
#include <hip/hip_runtime.h>

// Classwise circular-buffer queue update.
// occ_i = rank of proposal i within its class (original index order).
// slot  = (tail[l] + occ) % Q.  Proposal i is the FINAL writer of its slot
// iff occ >= k_l - Q.  => conflict-free scatter of proposal index into
// idx[C*Q], then one streaming gather pass building the output.

typedef float vf4 __attribute__((ext_vector_type(4)));
typedef int   vi4 __attribute__((ext_vector_type(4)));

#define HBLK 1024  // proposals per histogram block

// Init workspace: cnt = 0, idx = -1.  Grid-stride, vectorized.
__global__ void k_zero(int* __restrict__ idx, long long nIdx,
                       int* __restrict__ cnt, long long nCnt) {
    long long stride = (long long)gridDim.x * blockDim.x;
    long long g0 = (long long)blockIdx.x * blockDim.x + threadIdx.x;
    vi4* idx4 = (vi4*)idx;
    vi4* cnt4 = (vi4*)cnt;
    vi4 mone; mone.x = mone.y = mone.z = mone.w = -1;
    vi4 zero; zero.x = zero.y = zero.z = zero.w = 0;
    for (long long g = g0; g < nIdx / 4; g += stride) idx4[g] = mone;
    for (long long g = g0; g < nCnt / 4; g += stride) cnt4[g] = zero;
}

// Pure global-atomic histogram: cnt[(i/HBLK)*C + l]++.
__global__ void k_hist(const int* __restrict__ lab, int* __restrict__ cnt,
                       int N, int C) {
    int i = blockIdx.x * blockDim.x + threadIdx.x;
    if (i < N) {
        int l = lab[i];
        if (l >= 0 && l < C) atomicAdd(&cnt[(size_t)(i >> 10) * C + l], 1);
    }
}

// Column-wise exclusive prefix over blocks; total per label.
__global__ void k_prefix(int* __restrict__ cnt, int* __restrict__ ktot,
                         int C, int NB) {
    int l = blockIdx.x * blockDim.x + threadIdx.x;
    if (l >= C) return;
    int run = 0;
    for (int b = 0; b < NB; ++b) {
        int t = cnt[(size_t)b * C + l];
        cnt[(size_t)b * C + l] = run;  // exclusive prefix per (block,label)
        run += t;
    }
    ktot[l] = run;                     // total count per label
}

__global__ void k_slots(const int* __restrict__ lab, const int* __restrict__ tail,
                        const int* __restrict__ cnt, const int* __restrict__ ktot,
                        int* __restrict__ idx, int N, int C, int Q) {
    __shared__ __align__(16) int slab[HBLK];
    int b = blockIdx.x;
    int t = threadIdx.x;
    int i = b * HBLK + t;
    int l = (i < N) ? lab[i] : -1;
    slab[t] = l;
    __syncthreads();
    if (l < 0 || l >= C) return;
    // local rank within block: count slab[j]==l for j<t, 4 labels/iter.
    const vi4* slab4 = (const vi4*)slab;
    int local = 0;
    int nw = t >> 2;
    for (int w = 0; w < nw; ++w) {
        vi4 v = slab4[w];  // broadcast ds_read_b128
        local += (v.x == l) + (v.y == l) + (v.z == l) + (v.w == l);
    }
    for (int j = t & ~3; j < t; ++j) local += (slab[j] == l);
    int occ = cnt[(size_t)b * C + l] + local;
    int kk = ktot[l];
    if (occ >= kk - Q) {
        int s = (tail[l] + occ) % Q;
        if (s < 0) s += Q;            // python-style mod (positive divisor)
        idx[l * Q + s] = i;           // unique (class,slot) per qualifier
    }
}

// Grid-stride streaming gather; F4==64 fast path, 2 independent copies/iter.
__global__ void k_gather(const vf4* __restrict__ feat,
                         const vf4* __restrict__ queue,
                         const int* __restrict__ idx,
                         vf4* __restrict__ out,
                         long long total4, int F4) {
    long long stride = (long long)gridDim.x * blockDim.x;
    long long g = (long long)blockIdx.x * blockDim.x + threadIdx.x;
    if (F4 == 64) {
        for (; g + stride < total4; g += 2 * stride) {
            long long g2 = g + stride;
            int r1 = (int)(g >> 6),  c1 = (int)(g & 63);
            int r2 = (int)(g2 >> 6), c2 = (int)(g2 & 63);
            int id1 = idx[r1];
            int id2 = idx[r2];
            const vf4* s1 = (id1 >= 0) ? (feat + ((size_t)id1 << 6) + c1)
                                       : (queue + ((size_t)r1 << 6) + c1);
            const vf4* s2 = (id2 >= 0) ? (feat + ((size_t)id2 << 6) + c2)
                                       : (queue + ((size_t)r2 << 6) + c2);
            vf4 v1 = __builtin_nontemporal_load(s1);
            vf4 v2 = __builtin_nontemporal_load(s2);
            __builtin_nontemporal_store(v1, &out[g]);
            __builtin_nontemporal_store(v2, &out[g2]);
        }
        if (g < total4) {
            int r = (int)(g >> 6), c = (int)(g & 63);
            int id = idx[r];
            const vf4* s = (id >= 0) ? (feat + ((size_t)id << 6) + c)
                                     : (queue + ((size_t)r << 6) + c);
            vf4 v = __builtin_nontemporal_load(s);
            __builtin_nontemporal_store(v, &out[g]);
        }
    } else {
        for (; g < total4; g += stride) {
            int r = (int)(g / F4);
            int c = (int)(g - (long long)r * F4);
            int id = idx[r];
            const vf4* s = (id >= 0) ? (feat + (size_t)id * F4 + c)
                                     : (queue + (size_t)r * F4 + c);
            vf4 v = __builtin_nontemporal_load(s);
            __builtin_nontemporal_store(v, &out[g]);
        }
    }
}

extern "C" void kernel_launch(void* const* d_in, const int* in_sizes, int n_in,
                              void* d_out, int out_size, void* d_ws, size_t ws_size,
                              hipStream_t stream) {
    const float* feat  = (const float*)d_in[0];
    const float* queue = (const float*)d_in[1];
    const int*   lab   = (const int*)d_in[2];
    const int*   tail  = (const int*)d_in[3];

    const int N = in_sizes[2];
    const int C = in_sizes[3];
    const int F = in_sizes[0] / N;
    const int Q = in_sizes[1] / (C * F);
    const int NB = (N + HBLK - 1) / HBLK;

    int* idx  = (int*)d_ws;                    // C*Q
    int* cnt  = idx + (size_t)C * Q;           // NB*C
    int* ktot = cnt + (size_t)NB * C;          // C

    const long long R = (long long)C * Q;
    k_zero<<<2048, 256, 0, stream>>>(idx, R, cnt, (long long)NB * C);
    k_hist<<<(N + 255) / 256, 256, 0, stream>>>(lab, cnt, N, C);
    k_prefix<<<(C + 255) / 256, 256, 0, stream>>>(cnt, ktot, C, NB);
    k_slots<<<NB, HBLK, 0, stream>>>(lab, tail, cnt, ktot, idx, N, C, Q);

    const int F4 = F / 4;
    const long long total4 = R * F4;
    int gblocks = 2048;
    long long need = (total4 + 255) / 256;
    if (need < gblocks) gblocks = (int)need;
    k_gather<<<gblocks, 256, 0, stream>>>((const vf4*)feat,
                                          (const vf4*)queue, idx,
                                          (vf4*)d_out, total4, F4);
}

// Round 6
// 185.378 us; speedup vs baseline: 1.1867x; 1.0776x over previous
//
#include <hip/hip_runtime.h>

// Classwise circular-buffer queue update.
// occ_i = rank of proposal i within its class (original index order).
// slot  = (tail[l] + occ) % Q.  Proposal i is the FINAL writer of its slot
// iff occ >= k_l - Q (last min(k,Q) ranks cover distinct slots exactly once).
// => conflict-free scatter of proposal index into idx[C*Q], then one
// streaming gather pass building the output.

typedef float vf4 __attribute__((ext_vector_type(4)));
typedef int   vi4 __attribute__((ext_vector_type(4)));

#define HBLK 1024  // proposals per histogram block

// Zero own cnt row, then histogram this block's labels into it.
__global__ void k_hist(const int* __restrict__ lab, int* __restrict__ cnt,
                       int N, int C) {
    int b = blockIdx.x;
    int t = threadIdx.x;
    int* row = cnt + (size_t)b * C;
    for (int j = t; j < C; j += HBLK) row[j] = 0;
    __syncthreads();
    int i = b * HBLK + t;
    if (i < N) {
        int l = lab[i];
        if (l >= 0 && l < C) atomicAdd(&row[l], 1);
    }
}

// Column-wise exclusive prefix over blocks; total per label; init idx = -1.
__global__ void k_prefix(int* __restrict__ cnt, int* __restrict__ ktot,
                         int* __restrict__ idx, int C, int NB, int Q) {
    int l = blockIdx.x * blockDim.x + threadIdx.x;
    if (l >= C) return;
    int run = 0;
    for (int b = 0; b < NB; ++b) {
        int t = cnt[(size_t)b * C + l];
        cnt[(size_t)b * C + l] = run;  // exclusive prefix per (block,label)
        run += t;
    }
    ktot[l] = run;                     // total count per label
    for (int q = 0; q < Q; ++q) idx[l * Q + q] = -1;
}

__global__ void k_slots(const int* __restrict__ lab, const int* __restrict__ tail,
                        const int* __restrict__ cnt, const int* __restrict__ ktot,
                        int* __restrict__ idx, int N, int C, int Q) {
    __shared__ __align__(16) int slab[HBLK];
    int b = blockIdx.x;
    int t = threadIdx.x;
    int i = b * HBLK + t;
    int l = (i < N) ? lab[i] : -1;
    slab[t] = l;
    __syncthreads();
    if (l < 0 || l >= C) return;
    // local rank within block: count slab[j]==l for j<t, 4 labels/iter
    const vi4* slab4 = (const vi4*)slab;
    int local = 0;
    int nw = t >> 2;
    for (int w = 0; w < nw; ++w) {
        vi4 v = slab4[w];  // broadcast ds_read_b128
        local += (v.x == l) + (v.y == l) + (v.z == l) + (v.w == l);
    }
    for (int j = t & ~3; j < t; ++j) local += (slab[j] == l);
    int occ = cnt[(size_t)b * C + l] + local;
    int kk = ktot[l];
    if (occ >= kk - Q) {
        int s = (tail[l] + occ) % Q;
        if (s < 0) s += Q;            // python-style mod (positive divisor)
        idx[l * Q + s] = i;           // unique (class,slot) per qualifier
    }
}

// Direct-mapped gather (F==256): one wave per 1KB row, no loop.
// Plain (cached) loads; NT store (output never re-read).
__global__ void k_gather_d(const vf4* __restrict__ feat,
                           const vf4* __restrict__ queue,
                           const int* __restrict__ idx,
                           vf4* __restrict__ out, long long total4) {
    long long g = (long long)blockIdx.x * blockDim.x + threadIdx.x;
    if (g >= total4) return;
    int r = (int)(g >> 6);
    int c = (int)(g & 63);
    int id = idx[r];  // one line per wave, broadcast
    const vf4* src = (id >= 0) ? (feat + ((size_t)id << 6) + c)
                               : (queue + ((size_t)r << 6) + c);
    __builtin_nontemporal_store(*src, &out[g]);
}

// Generic fallback (any F divisible by 4).
__global__ void k_gather_g(const vf4* __restrict__ feat,
                           const vf4* __restrict__ queue,
                           const int* __restrict__ idx,
                           vf4* __restrict__ out,
                           long long total4, int F4) {
    long long stride = (long long)gridDim.x * blockDim.x;
    for (long long g = (long long)blockIdx.x * blockDim.x + threadIdx.x;
         g < total4; g += stride) {
        int r = (int)(g / F4);
        int c = (int)(g - (long long)r * F4);
        int id = idx[r];
        const vf4* src = (id >= 0) ? (feat + (size_t)id * F4 + c)
                                   : (queue + (size_t)r * F4 + c);
        __builtin_nontemporal_store(*src, &out[g]);
    }
}

extern "C" void kernel_launch(void* const* d_in, const int* in_sizes, int n_in,
                              void* d_out, int out_size, void* d_ws, size_t ws_size,
                              hipStream_t stream) {
    const float* feat  = (const float*)d_in[0];
    const float* queue = (const float*)d_in[1];
    const int*   lab   = (const int*)d_in[2];
    const int*   tail  = (const int*)d_in[3];

    const int N = in_sizes[2];
    const int C = in_sizes[3];
    const int F = in_sizes[0] / N;
    const int Q = in_sizes[1] / (C * F);
    const int NB = (N + HBLK - 1) / HBLK;

    int* idx  = (int*)d_ws;                    // C*Q
    int* cnt  = idx + (size_t)C * Q;           // NB*C
    int* ktot = cnt + (size_t)NB * C;          // C

    k_hist<<<NB, HBLK, 0, stream>>>(lab, cnt, N, C);
    k_prefix<<<(C + 255) / 256, 256, 0, stream>>>(cnt, ktot, idx, C, NB, Q);
    k_slots<<<NB, HBLK, 0, stream>>>(lab, tail, cnt, ktot, idx, N, C, Q);

    const long long R = (long long)C * Q;
    const int F4 = F / 4;
    const long long total4 = R * F4;
    if (F == 256) {
        const int blocks = (int)((total4 + 511) / 512);
        k_gather_d<<<blocks, 512, 0, stream>>>((const vf4*)feat,
                                               (const vf4*)queue, idx,
                                               (vf4*)d_out, total4);
    } else {
        int gblocks = 2048;
        long long need = (total4 + 255) / 256;
        if (need < gblocks) gblocks = (int)need;
        k_gather_g<<<gblocks, 256, 0, stream>>>((const vf4*)feat,
                                                (const vf4*)queue, idx,
                                                (vf4*)d_out, total4, F4);
    }
}